// Round 2
// baseline (219.605 us; speedup 1.0000x reference)
//
#include <hip/hip_runtime.h>
#include <hip/hip_fp16.h>

// AdultConnectomeNetwork: 3 layers of  x = A @ (W @ x) + bias
// A and W share the same sorted-COO pattern. N=50000, NNZ=800000, B=64.
//
// R4 (this round): gathers are latency-bound on a 6.4MB fp16 table that does
// NOT fit a 4MB per-XCD L2 (~40% miss to L3 at 3x the latency). Split the 64
// columns into two compact 32-col planes (3.2MB each). plane = blockIdx.x & 1
// -> with round-robin block->XCD dispatch, even XCDs only touch plane 0 and
// odd XCDs plane 1: each XCD's gather working set becomes L2-resident.
//  - 8 lanes per row (8B/lane = 64B/edge), 32 rows per 256-thread block
//  - 16-edge batches via one 16B lane-striped NT load (2 edges/lane)
//  - next-batch prefetch before consuming current gathers
//  - NT loads on edge stream, NT stores on y: protect x-plane L2 residency

typedef float f32x4 __attribute__((ext_vector_type(4)));
typedef unsigned long long u64x2 __attribute__((ext_vector_type(2)));

__global__ void build_row_ptr_kernel(const int* __restrict__ rows, int nnz,
                                     int n, int* __restrict__ row_ptr) {
    int r = blockIdx.x * blockDim.x + threadIdx.x;
    if (r > n) return;
    int lo = 0, hi = nnz;
    while (lo < hi) {
        int mid = (lo + hi) >> 1;
        if (rows[mid] < r) lo = mid + 1; else hi = mid;
    }
    row_ptr[r] = lo;
}

// fp32 [N][64] -> two fp16 planes of 32 cols each: xh[p][row*8+lane] covers
// cols 32p+4*lane .. +4. One thread per float4 (4 cols).
__global__ void f32_to_f16_planes_kernel(const float4* __restrict__ in,
                                         uint2* __restrict__ out,  // 2 planes
                                         int n) {
    int i = blockIdx.x * blockDim.x + threadIdx.x;  // over n*16 float4s
    if (i >= n * 16) return;
    int row = i >> 4, q = i & 15;
    int plane = q >> 3, lane = q & 7;
    float4 v = in[i];
    __half2 h0 = __floats2half2_rn(v.x, v.y);
    __half2 h1 = __floats2half2_rn(v.z, v.w);
    uint2 r;
    r.x = *(unsigned int*)&h0;
    r.y = *(unsigned int*)&h1;
    out[(size_t)plane * n * 8 + row * 8 + lane] = r;
}

// Build packed (col, val_bits) 8B words for both matrices in one pass.
__global__ void pack_kernel(const float* __restrict__ wv,
                            const float* __restrict__ av,
                            const int* __restrict__ cols, int nnz,
                            unsigned long long* __restrict__ pw,
                            unsigned long long* __restrict__ pa) {
    int i = blockIdx.x * blockDim.x + threadIdx.x;
    if (i >= nnz) return;
    unsigned long long c = (unsigned)cols[i];
    pw[i] = c | ((unsigned long long)__float_as_uint(wv[i]) << 32);
    pa[i] = c | ((unsigned long long)__float_as_uint(av[i]) << 32);
}

// Load edges i0, i0+1 (i0 even -> 16B aligned). Zero val bits outside [e0,e1).
__device__ __forceinline__ void load_pair(int4& d, const unsigned long long* p,
                                          int i0, int e0, int e1) {
    unsigned long long q0 = 0, q1 = 0;
    if (i0 + 1 < e1) {
        u64x2 q = __builtin_nontemporal_load((const u64x2*)(p + i0));
        q0 = q.x; q1 = q.y;
    } else if (i0 < e1) {
        q0 = __builtin_nontemporal_load(p + i0);
    }
    if (i0 < e0) q0 &= 0xFFFFFFFFull;  // low-guard (first aligned batch only)
    d.x = (int)q0; d.y = (int)(q0 >> 32);
    d.z = (int)q1; d.w = (int)(q1 >> 32);
}

// y_plane[r,:] = sum_e val[e] * x_plane[col[e],:]  (+bias[r]).
// 8 lanes per row; lane l owns 4 cols (one uint2 of 4 halves) of its plane.
template <bool ADD_BIAS, bool OUT_F32>
__global__ __launch_bounds__(256, 6)
void spmm_f16_kernel(const unsigned long long* __restrict__ packed,
                     const int* __restrict__ row_ptr,
                     const uint2* __restrict__ xin0,   // plane 0 base, [n*8]
                     const float* __restrict__ bias,
                     unsigned long long* __restrict__ yout16,  // plane 0 base
                     f32x4* __restrict__ yout32,               // [n*16] fp32x4
                     int n) {
    const int bid   = blockIdx.x;
    const int plane = bid & 1;          // even XCDs -> plane 0, odd -> plane 1
    const int row   = (bid >> 1) * 32 + (threadIdx.x >> 3);
    const int lane  = threadIdx.x & 7;
    const int base  = threadIdx.x & 56;  // 8-lane group base within the wave
    if (row >= n) return;

    const uint2* __restrict__ xin = xin0 + (size_t)plane * n * 8;

    const int e0 = row_ptr[row];
    const int e1 = row_ptr[row + 1];

    float4 acc = make_float4(0.f, 0.f, 0.f, 0.f);

    if (e0 < e1) {
        const int eb = e0 & ~1;  // 16B-align the batch start
        int4 cur;
        load_pair(cur, packed, eb + 2 * lane, e0, e1);

        for (int e = eb; e < e1; e += 16) {
            // prefetch next batch's edge info (overlaps this batch's gathers)
            int4 nxt = make_int4(0, 0, 0, 0);
            const int en = e + 16;
            if (en < e1) load_pair(nxt, packed, en + 2 * lane, e0, e1);

            // issue all 16 gathers for this batch
            uint2 raw[16];
#pragma unroll
            for (int j = 0; j < 16; ++j) {
                const int c = __shfl((j & 1) ? cur.z : cur.x, base + (j >> 1));
                raw[j] = xin[c * 8 + lane];   // 8B/lane, 64B/edge, one segment
            }
            // consume: val broadcast (DS pipe) interleaves with vmcnt waits
#pragma unroll
            for (int j = 0; j < 16; ++j) {
                const float v = __uint_as_float(
                    __shfl((j & 1) ? cur.w : cur.y, base + (j >> 1)));
                const __half2 h0 = *(const __half2*)&raw[j].x;
                const __half2 h1 = *(const __half2*)&raw[j].y;
                const float2 f0 = __half22float2(h0);
                const float2 f1 = __half22float2(h1);
                acc.x += v * f0.x;
                acc.y += v * f0.y;
                acc.z += v * f1.x;
                acc.w += v * f1.y;
            }
            cur = nxt;
        }
    }

    if (ADD_BIAS) {
        const float b = bias[row];
        acc.x += b; acc.y += b; acc.z += b; acc.w += b;
    }

    if (OUT_F32) {
        f32x4 o;
        o.x = acc.x; o.y = acc.y; o.z = acc.z; o.w = acc.w;
        // plane p covers float4 slots [8p, 8p+8) of the row
        __builtin_nontemporal_store(o, &yout32[row * 16 + plane * 8 + lane]);
    } else {
        __half2 h0 = __floats2half2_rn(acc.x, acc.y);
        __half2 h1 = __floats2half2_rn(acc.z, acc.w);
        unsigned long long r = (unsigned long long)(*(unsigned int*)&h0)
                             | ((unsigned long long)(*(unsigned int*)&h1) << 32);
        __builtin_nontemporal_store(
            r, &(yout16 + (size_t)plane * n * 8)[row * 8 + lane]);
    }
}

extern "C" void kernel_launch(void* const* d_in, const int* in_sizes, int n_in,
                              void* d_out, int out_size, void* d_ws, size_t ws_size,
                              hipStream_t stream) {
    const float* x_in     = (const float*)d_in[0];  // (N, 64)
    const float* adj_vals = (const float*)d_in[1];  // (NNZ,)
    const float* w_vals   = (const float*)d_in[2];  // (NNZ,)
    const float* bias     = (const float*)d_in[3];  // (N,)
    const int*   rows     = (const int*)d_in[4];    // (NNZ,) sorted
    const int*   cols     = (const int*)d_in[5];    // (NNZ,)
    // d_in[6] = n_layers (device scalar); structurally 3.

    const int N   = in_sizes[3];
    const int NNZ = in_sizes[1];

    // Workspace: row_ptr | xh (2 planes, N*64 fp16) | yh (2 planes) | pw | pa
    char* ws = (char*)d_ws;
    int* row_ptr = (int*)ws;
    size_t off = ((size_t)(N + 1) * sizeof(int) + 255) & ~(size_t)255;
    uint2* xh = (uint2*)(ws + off);                 off += (size_t)N * 16 * 8;
    uint2* yh = (uint2*)(ws + off);                 off += (size_t)N * 16 * 8;
    unsigned long long* pw = (unsigned long long*)(ws + off); off += (size_t)NNZ * 8;
    unsigned long long* pa = (unsigned long long*)(ws + off);

    // 1) CSR row pointers
    {
        int threads = 256;
        int blocks = (N + 1 + threads - 1) / threads;
        build_row_ptr_kernel<<<blocks, threads, 0, stream>>>(rows, NNZ, N, row_ptr);
    }
    // 2) input fp32 -> two fp16 planes
    {
        int n16 = N * 16;
        int threads = 256;
        int blocks = (n16 + threads - 1) / threads;
        f32_to_f16_planes_kernel<<<blocks, threads, 0, stream>>>(
            (const float4*)x_in, xh, N);
    }
    // 3) pack (col,val) for W and A
    {
        int threads = 256;
        int blocks = (NNZ + threads - 1) / threads;
        pack_kernel<<<blocks, threads, 0, stream>>>(w_vals, adj_vals, cols, NNZ, pw, pa);
    }

    const int threads = 256;                       // 32 rows per block
    const int nbp = (N + 31) / 32;                 // row-blocks per plane
    const int blocks = 2 * nbp;                    // x2 planes, plane = bid&1
    f32x4* out32 = (f32x4*)d_out;

    // layer 1: yh = W@xh ; xh = A@yh + b
    spmm_f16_kernel<false, false><<<blocks, threads, 0, stream>>>(pw, row_ptr,
        xh, nullptr, (unsigned long long*)yh, nullptr, N);
    spmm_f16_kernel<true, false><<<blocks, threads, 0, stream>>>(pa, row_ptr,
        yh, bias, (unsigned long long*)xh, nullptr, N);
    // layer 2
    spmm_f16_kernel<false, false><<<blocks, threads, 0, stream>>>(pw, row_ptr,
        xh, nullptr, (unsigned long long*)yh, nullptr, N);
    spmm_f16_kernel<true, false><<<blocks, threads, 0, stream>>>(pa, row_ptr,
        yh, bias, (unsigned long long*)xh, nullptr, N);
    // layer 3: last SpMM writes fp32 to d_out
    spmm_f16_kernel<false, false><<<blocks, threads, 0, stream>>>(pw, row_ptr,
        xh, nullptr, (unsigned long long*)yh, nullptr, N);
    spmm_f16_kernel<true, true><<<blocks, threads, 0, stream>>>(pa, row_ptr,
        yh, bias, nullptr, out32, N);
}